// Round 9
// baseline (715.250 us; speedup 1.0000x reference)
//
#include <hip/hip_runtime.h>
#include <hip/hip_bf16.h>
#include <cmath>

typedef unsigned short u16;
typedef __attribute__((ext_vector_type(8))) short bf16x8;
typedef __attribute__((ext_vector_type(4))) float f32x4;
typedef __attribute__((ext_vector_type(4))) unsigned short u16x4;

// Problem constants: B=8, C=128, H=128, WIN=4, K=3, WS=64, L=16384
// Workspace layout (bytes):
#define OFF_BAR   0u          // software grid-barrier counters (cnt @0, gen @64)
#define OFF_WW    81920u      // 32 f32
#define OFF_R     82048u      // 4*128*9 f32 = 18432
#define OFF_FSUM  100480u     // 128 f32
#define OFF_GKT   100992u     // 4*128*128 f32 = 262144
#define OFF_A     363136u     // 2359296
#define OFF_P     2722432u    // 2359296
#define OFF_M     5081728u    // rowT (1 MB) — exclusive, no aliasing
#define OFF_KEFF  7441024u    // keff u16 2359296 — exclusive (alias removed)
#define OFF_XPAD  9800320u    // [b][130][130][128] u16 = 34611200

__device__ __forceinline__ u16 f2bf(float f) {
  union { float f; unsigned int u; } v; v.f = f;
  unsigned int r = v.u + 0x7FFFu + ((v.u >> 16) & 1u);
  return (u16)(r >> 16);
}

// Sense-reversal grid barrier. Safe because grid(512) == exact residency
// (2 blocks/CU forced by launch_bounds + 66.5KB LDS). __syncthreads drains
// each wave's vmcnt pre-arrive; thread0's release fence writes back the XCD
// L2 (covers all the block's stores); acquire fence after the flip
// invalidates L1/L2 so post-barrier reads see fresh data.
__device__ __forceinline__ void grid_barrier(unsigned* cnt, unsigned* gen) {
  __syncthreads();
  if (threadIdx.x == 0) {
    __threadfence();   // release: wb L2 to coherent point
    unsigned g = __hip_atomic_load(gen, __ATOMIC_RELAXED, __HIP_MEMORY_SCOPE_AGENT);
    unsigned a = __hip_atomic_fetch_add(cnt, 1u, __ATOMIC_ACQ_REL, __HIP_MEMORY_SCOPE_AGENT);
    if (a == 511u) {
      __hip_atomic_store(cnt, 0u, __ATOMIC_RELAXED, __HIP_MEMORY_SCOPE_AGENT);
      __hip_atomic_store(gen, g + 1u, __ATOMIC_RELEASE, __HIP_MEMORY_SCOPE_AGENT);
    } else {
      while (__hip_atomic_load(gen, __ATOMIC_ACQUIRE, __HIP_MEMORY_SCOPE_AGENT) == g)
        __builtin_amdgcn_s_sleep(4);
    }
    __threadfence();   // acquire: invalidate L1/L2
  }
  __syncthreads();
}

// ---------------------------------------------------------------------------
// MEGA: whole pipeline, ONE normal dispatch, 3 software grid barriers.
// Phase bodies = round-7 proven kernels (kd1 / k2-direct / k45 / k6).
// ---------------------------------------------------------------------------
__global__ __launch_bounds__(256, 2) void mega(
    const float* __restrict__ x, const float* __restrict__ conv1_w,
    const float* __restrict__ dc_w, const float* __restrict__ dc_b,
    const float* __restrict__ l1_w, const float* __restrict__ l1_b,
    const float* __restrict__ l2_w, const float* __restrict__ l2_b,
    const float* __restrict__ gk_w, const float* __restrict__ gk_b,
    const float* __restrict__ fusion_w, const float* __restrict__ fusion_b,
    float* __restrict__ out, char* __restrict__ ws) {
  unsigned* bcnt = (unsigned*)(ws + OFF_BAR);
  unsigned* bgen = (unsigned*)(ws + OFF_BAR + 64);
  float* wwp  = (float*)(ws + OFF_WW);
  float* R    = (float*)(ws + OFF_R);
  float* fsum = (float*)(ws + OFF_FSUM);
  float* gkT  = (float*)(ws + OFF_GKT);
  float* A    = (float*)(ws + OFF_A);
  float* P    = (float*)(ws + OFF_P);
  float* rowT = (float*)(ws + OFF_M);
  u16* keff   = (u16*)(ws + OFF_KEFF);
  u16* xpad   = (u16*)(ws + OFF_XPAD);

  __shared__ __align__(16) u16 alds[130 * 128];   // 33,280 B
  __shared__ __align__(16) u16 apad[256];         // DMA tail guard
  __shared__ __align__(16) u16 wlds[128 * 128];   // 32,768 B
  (void)apad;

  const int bid = blockIdx.x;   // 0..511
  const int tid = threadIdx.x;

  // ======================= Phase 0: prep =======================
  for (int unit = bid; unit < 1891; unit += 512) {
    if (unit < 18) {
      int gid = unit * 256 + tid;
      int w = gid / 1152, m = gid % 1152;
      float s = 0.f;
      for (int o = 0; o < 128; ++o)
        s += dc_w[w * 128 + o] * conv1_w[(size_t)(w * 128 + o) * 1152 + m];
      R[gid] = s;
    } else if (unit < 274) {
      int gid = (unit - 18) * 256 + tid;
      int w = gid >> 14, j = (gid >> 7) & 127, c = gid & 127;
      gkT[gid] = gk_w[c * 512 + w * 128 + j];
    } else if (unit == 274) {
      if (tid < 128) {
        float s = 0.f;
        for (int oc = 0; oc < 128; ++oc) s += fusion_w[tid * 640 + 512 + oc];
        fsum[tid] = s;
      }
    } else if (unit < 851) {
      int gid = (unit - 275) * 256 + tid;
      int w = gid / 36864;
      int rem = gid % 36864;
      int o = rem / 288;
      int m = (rem % 288) * 4;
      const float* fw1 = fusion_w + o * 640 + w * 128;
      const float* fw4 = fusion_w + o * 640 + 512;
      const float* cw = conv1_w + (size_t)w * 128 * 1152 + m;
      float a0 = 0, a1 = 0, a2 = 0, a3 = 0, p0 = 0, p1 = 0, p2 = 0, p3 = 0;
      for (int oc = 0; oc < 128; ++oc) {
        float f1 = fw1[oc], f4 = fw4[oc];
        float4 cv = *(const float4*)(cw + (size_t)oc * 1152);
        a0 += f1 * cv.x; a1 += f1 * cv.y; a2 += f1 * cv.z; a3 += f1 * cv.w;
        p0 += f4 * cv.x; p1 += f4 * cv.y; p2 += f4 * cv.z; p3 += f4 * cv.w;
      }
      float4* Ao = (float4*)(A + (size_t)(w * 128 + o) * 1152 + m);
      float4* Po = (float4*)(P + (size_t)(w * 128 + o) * 1152 + m);
      *Ao = make_float4(a0, a1, a2, a3);
      *Po = make_float4(p0, p1, p2, p3);
    } else {
      // x-side: pad to bf16 + row-sum partials (no atomics, no col buffers)
      const int kb = unit - 851;                  // 0..1039
      const int rp = kb % 130;
      const int b = kb / 130;
      const size_t xpb = ((size_t)b * 130 + rp) * 16640;
      if (rp == 0 || rp == 129) {
        const bf16x8 z = {0, 0, 0, 0, 0, 0, 0, 0};
        #pragma unroll
        for (int rr = 0; rr < 8; ++rr)
          *(bf16x8*)(xpad + xpb + (size_t)(rr * 256 + tid) * 8) = z;
        if (tid < 32)
          *(bf16x8*)(xpad + xpb + (size_t)(2048 + tid) * 8) = z;
      } else {
        const int r = rp - 1;
        if (tid < 32) {
          *(u16x4*)(xpad + xpb + tid * 4) = (u16x4){0, 0, 0, 0};
        } else if (tid < 64) {
          *(u16x4*)(xpad + xpb + 129 * 128 + (tid - 32) * 4) = (u16x4){0, 0, 0, 0};
        }
        const int s = tid >> 5;          // pixel strip 0..7
        const int cg2 = tid & 31;        // channel group
        const int c0 = cg2 * 4;
        const float* xr = x + ((size_t)b * 16384 + (size_t)r * 128) * 128;
        f32x4 sum = {0.f, 0.f, 0.f, 0.f};
        #pragma unroll
        for (int qi = 0; qi < 16; ++qi) {
          const int q = s * 16 + qi;
          f32x4 v = *(const f32x4*)(xr + (size_t)q * 128 + c0);
          sum += v;
          u16x4 st = { f2bf(v[0]), f2bf(v[1]), f2bf(v[2]), f2bf(v[3]) };
          *(u16x4*)(xpad + xpb + (size_t)(q + 1) * 128 + c0) = st;
        }
        f32x4* ls = (f32x4*)alds;        // [8][32]
        ls[s * 32 + cg2] = sum;
        __syncthreads();
        if (tid < 64) {
          const int h = tid >> 5, g = tid & 31;
          f32x4 T = ls[(h * 4 + 0) * 32 + g] + ls[(h * 4 + 1) * 32 + g]
                  + ls[(h * 4 + 2) * 32 + g] + ls[(h * 4 + 3) * 32 + g];
          // rowT[b][r][half h][c]
          *(f32x4*)(rowT + (((size_t)b * 128 + r) * 2 + h) * 128 + g * 4) = T;
        }
      }
    }
    __syncthreads();   // protect LDS alias across units
  }
  grid_barrier(bcnt, bgen);

  // ======================= Phase 1: ww gate (blocks 0..7) ==================
  if (bid < 8) {
    const int b = bid;
    const int w = tid >> 6, lane = tid & 63;
    float* red4 = (float*)alds;
    const int i = w >> 1, j = w & 1;
    float partial = 0.f;
    #pragma unroll
    for (int k = 0; k < 2; ++k) {
      const int c = lane * 2 + k;
      const size_t rbase = ((size_t)b * 128 + i * 64) * 2 + j;
      float T = 0.f;
      #pragma unroll 4
      for (int ri = 0; ri < 64; ++ri) T += rowT[(rbase + (size_t)ri * 2) * 128 + c];
      const float rF = rowT[rbase * 128 + c];
      const float rL = rowT[(rbase + 126) * 128 + c];
      // column sums + corners direct from x (input is never written -> no staleness)
      const float* xcol = x + ((size_t)b * 16384 + (size_t)(i * 64) * 128 + j * 64) * 128 + c;
      float cF = 0.f, cL = 0.f;
      #pragma unroll 4
      for (int ri = 0; ri < 64; ++ri) {
        cF += xcol[(size_t)ri * 16384];
        cL += xcol[(size_t)ri * 16384 + 63 * 128];
      }
      const float c00 = xcol[0];
      const float c0L = xcol[63 * 128];
      const float cL0 = xcol[(size_t)63 * 16384];
      const float cLL = xcol[(size_t)63 * 16384 + 63 * 128];
      float S[9];
      S[0] = T - rL - cL + cLL;
      S[1] = T - rL;
      S[2] = T - rL - cF + cL0;
      S[3] = T - cL;
      S[4] = T;
      S[5] = T - cF;
      S[6] = T - rF - cL + c0L;
      S[7] = T - rF;
      S[8] = T - rF - cF + c00;
      const float* Rp = R + (w * 128 + c) * 9;
      #pragma unroll
      for (int t = 0; t < 9; ++t) partial += S[t] * Rp[t];
    }
    for (int off = 32; off > 0; off >>= 1) partial += __shfl_xor(partial, off, 64);
    if (lane == 0) red4[w] = partial;
    __syncthreads();
    if (tid == 0) {
      float ww0[4];
      #pragma unroll
      for (int w2 = 0; w2 < 4; ++w2) ww0[w2] = red4[w2] * (1.f / 4096.f) + dc_b[w2];
      float h1[16];
      for (int i2 = 0; i2 < 16; ++i2) {
        float s = l1_b[i2];
        #pragma unroll
        for (int w2 = 0; w2 < 4; ++w2) s += l1_w[i2 * 4 + w2] * ww0[w2];
        h1[i2] = 0.5f * s * (1.f + erff(s * 0.70710678118654752f));
      }
      for (int w2 = 0; w2 < 4; ++w2) {
        float s = l2_b[w2];
        for (int i2 = 0; i2 < 16; ++i2) s += l2_w[w2 * 16 + i2] * h1[i2];
        wwp[b * 4 + w2] = 1.f / (1.f + expf(-s));
      }
    }
  }
  grid_barrier(bcnt, bgen);

  // ======================= Phase 2: keff (k45 units) =======================
  for (int unit = bid; unit < 576; unit += 512) {
    __syncthreads();
    const int t = unit >> 6;
    const int o0 = (unit & 63) * 2;
    float* pl = (float*)alds;              // [2][4][128]
    float* al = pl + 1024;                 // [2][4][128]
    float* red = (float*)wlds;             // [2][2][4][128]
    #pragma unroll
    for (int rr = 0; rr < 4; ++rr) {
      const int idx = rr * 256 + tid;
      const int oi = idx >> 9, w = (idx >> 7) & 3, j = idx & 127;
      const size_t src = (size_t)(w * 128 + o0 + oi) * 1152 + j * 9 + t;
      pl[(oi * 4 + w) * 128 + j] = P[src];
      al[(oi * 4 + w) * 128 + j] = A[src];
    }
    __syncthreads();
    const int c = tid & 127, jh = tid >> 7;
    float acc[2][4];
    #pragma unroll
    for (int oi = 0; oi < 2; ++oi)
      #pragma unroll
      for (int w = 0; w < 4; ++w) acc[oi][w] = 0.f;
    const float* g = gkT + c;
    #pragma unroll 4
    for (int j = jh * 64; j < jh * 64 + 64; ++j) {
      const float g0 = g[0 * 16384 + j * 128];
      const float g1 = g[1 * 16384 + j * 128];
      const float g2 = g[2 * 16384 + j * 128];
      const float g3 = g[3 * 16384 + j * 128];
      #pragma unroll
      for (int oi = 0; oi < 2; ++oi) {
        acc[oi][0] += pl[(oi * 4 + 0) * 128 + j] * g0;
        acc[oi][1] += pl[(oi * 4 + 1) * 128 + j] * g1;
        acc[oi][2] += pl[(oi * 4 + 2) * 128 + j] * g2;
        acc[oi][3] += pl[(oi * 4 + 3) * 128 + j] * g3;
      }
    }
    #pragma unroll
    for (int oi = 0; oi < 2; ++oi)
      #pragma unroll
      for (int w = 0; w < 4; ++w) red[((jh * 2 + oi) * 4 + w) * 128 + c] = acc[oi][w];
    __syncthreads();
    const int oi2 = tid >> 7, c2 = tid & 127;
    float m[4];
    #pragma unroll
    for (int w = 0; w < 4; ++w)
      m[w] = red[((0 * 2 + oi2) * 4 + w) * 128 + c2]
           + red[((1 * 2 + oi2) * 4 + w) * 128 + c2]
           + al[(oi2 * 4 + w) * 128 + c2];
    const float base = fsum[o0 + oi2] * gk_b[c2];
    #pragma unroll
    for (int b = 0; b < 8; ++b) {
      float r = base;
      #pragma unroll
      for (int w = 0; w < 4; ++w) r += wwp[b * 4 + w] * m[w];
      keff[(size_t)b * 147456 + (size_t)t * 16384 + (o0 + oi2) * 128 + c2] = f2bf(r);
    }
  }
  grid_barrier(bcnt, bgen);

  // ======================= Phase 3: conv (k6, 2 rows/block) ================
  {
    const int b = bid & 7;            // XCD affinity: batch <-> XCD
    const int ph = bid >> 3;          // 0..63 -> rows 2*ph, 2*ph+1
    const int wid = tid >> 6;
    const int lane = tid & 63;
    const int wm = (wid & 1) * 64;
    const int wn = (wid >> 1) * 64;
    const int quad = lane >> 4;
    const int l16 = lane & 15;
    const u16* kb = keff + (size_t)b * 147456;
    const u16* xb = xpad + (size_t)b * 130 * 16640;
    bf16x8 streg[8];

    for (int rr2 = 0; rr2 < 2; ++rr2) {
      const int p = ph * 2 + rr2;
      f32x4 acc[4][4];
      #pragma unroll
      for (int i = 0; i < 4; ++i)
        #pragma unroll
        for (int j = 0; j < 4; ++j)
          acc[i][j] = (f32x4){0.f, 0.f, 0.f, 0.f};

      auto stage_W_load = [&](int tap) {
        const u16* src = kb + tap * 16384;
        #pragma unroll
        for (int it = 0; it < 8; ++it) {
          const int chunk = it * 256 + tid;
          const int gs = chunk ^ ((chunk >> 4) & 7);
          streg[it] = *(const bf16x8*)(src + gs * 8);
        }
      };
      auto stage_W_write = [&]() {
        #pragma unroll
        for (int it = 0; it < 8; ++it)
          *(bf16x8*)(wlds + (it * 256 + tid) * 8) = streg[it];
      };
      auto stage_A_dma = [&](int prow) {
        const u16* src = xb + (size_t)prow * 16640;
        #pragma unroll
        for (int r = 0; r < 8; ++r) {
          const int chunk = (wid * 8 + r) * 64 + lane;
          const int gs = chunk ^ ((chunk >> 4) & 7);
          __builtin_amdgcn_global_load_lds(
              (const __attribute__((address_space(1))) unsigned int*)(src + (size_t)gs * 8),
              (__attribute__((address_space(3))) unsigned int*)(alds + (wid * 8 + r) * 512),
              16, 0, 0);
        }
        if (tid < 32) {
          const int chunk = 2048 + tid;
          const int gs = chunk ^ ((chunk >> 4) & 7);
          __builtin_amdgcn_global_load_lds(
              (const __attribute__((address_space(1))) unsigned int*)(src + (size_t)gs * 8),
              (__attribute__((address_space(3))) unsigned int*)(alds + 2048 * 8),
              16, 0, 0);
        }
      };

      stage_W_load(0);
      stage_A_dma(p);
      stage_W_write();
      __syncthreads();   // drains vmcnt -> DMA complete, W visible

      for (int tap = 0; tap < 9; ++tap) {
        if (tap < 8) stage_W_load(tap + 1);
        const int dw = tap % 3 - 1;
        const int pixoff = 1 + dw;
        #pragma unroll
        for (int kc = 0; kc < 4; ++kc) {
          const int c0 = kc * 32 + quad * 8;
          bf16x8 a[4], bb[4];
          #pragma unroll
          for (int i = 0; i < 4; ++i) {
            const int pix = pixoff + wm + i * 16 + l16;
            const int off = (pix * 128 + c0) ^ ((pix & 7) << 3);
            a[i] = *(const bf16x8*)(alds + off);
          }
          #pragma unroll
          for (int j = 0; j < 4; ++j) {
            const int row = wn + j * 16 + l16;
            const int off = (row * 128 + c0) ^ ((row & 7) << 3);
            bb[j] = *(const bf16x8*)(wlds + off);
          }
          #pragma unroll
          for (int i = 0; i < 4; ++i)
            #pragma unroll
            for (int j = 0; j < 4; ++j)
              acc[i][j] = __builtin_amdgcn_mfma_f32_16x16x32_bf16(a[i], bb[j], acc[i][j], 0, 0, 0);
        }
        __syncthreads();
        if (tap < 8) {
          stage_W_write();
          if (tap % 3 == 2) stage_A_dma(p + (tap + 1) / 3);
          __syncthreads();
        }
      }

      float fb[4];
      #pragma unroll
      for (int j = 0; j < 4; ++j) fb[j] = fusion_b[wn + j * 16 + l16];
      float* outb = out + ((size_t)b * 16384 + (size_t)p * 128) * 128;
      #pragma unroll
      for (int i = 0; i < 4; ++i)
        #pragma unroll
        for (int r = 0; r < 4; ++r) {
          const int m = wm + i * 16 + quad * 4 + r;
          #pragma unroll
          for (int j = 0; j < 4; ++j)
            outb[(size_t)m * 128 + (wn + j * 16 + l16)] = acc[i][j][r] + fb[j];
        }
    }
  }
}

extern "C" void kernel_launch(void* const* d_in, const int* in_sizes, int n_in,
                              void* d_out, int out_size, void* d_ws, size_t ws_size,
                              hipStream_t stream) {
  const float* x        = (const float*)d_in[0];
  const float* conv1_w  = (const float*)d_in[1];
  const float* dc_w     = (const float*)d_in[2];
  const float* dc_b     = (const float*)d_in[3];
  const float* l1_w     = (const float*)d_in[4];
  const float* l1_b     = (const float*)d_in[5];
  const float* l2_w     = (const float*)d_in[6];
  const float* l2_b     = (const float*)d_in[7];
  const float* gk_w     = (const float*)d_in[8];
  const float* gk_b     = (const float*)d_in[9];
  const float* fusion_w = (const float*)d_in[10];
  const float* fusion_b = (const float*)d_in[11];
  float* out = (float*)d_out;
  char* ws = (char*)d_ws;

  hipMemsetAsync(ws + OFF_BAR, 0, 128, stream);   // zero barrier cnt/gen each replay
  mega<<<512, 256, 0, stream>>>(x, conv1_w, dc_w, dc_b, l1_w, l1_b, l2_w, l2_b,
                                gk_w, gk_b, fusion_w, fusion_b, out, ws);
}

// Round 10
// 217.193 us; speedup vs baseline: 3.2932x; 3.2932x over previous
//
#include <hip/hip_runtime.h>
#include <hip/hip_bf16.h>
#include <cmath>

typedef unsigned short u16;
typedef __attribute__((ext_vector_type(8))) short bf16x8;
typedef __attribute__((ext_vector_type(4))) float f32x4;
typedef __attribute__((ext_vector_type(4))) unsigned short u16x4;

// Problem constants: B=8, C=128, H=128, WIN=4, K=3, WS=64, L=16384
// Workspace layout (bytes):
#define OFF_WW    81920u      // 32 f32
#define OFF_R     82048u      // 4*128*9 f32 = 18432
#define OFF_FSUM  100480u     // 128 f32
#define OFF_GKT   100992u     // 4*128*128 f32 = 262144
#define OFF_A     363136u     // 2359296
#define OFF_P     2722432u    // 2359296
#define OFF_M     5081728u    // rowT (1 MB) + colF (1 MB)
#define OFF_KEFF  7441024u    // keff u16 2359296; first 1 MB doubles as colL (D1->D2, stream-ordered)
#define OFF_XPAD  9800320u    // [b][130][130][128] u16 = 34611200

__device__ __forceinline__ u16 f2bf(float f) {
  union { float f; unsigned int u; } v; v.f = f;
  unsigned int r = v.u + 0x7FFFu + ((v.u >> 16) & 1u);
  return (u16)(r >> 16);
}

// ---------------------------------------------------------------------------
// kd1: merged weight-side prep AND x-side pad/stats (one dispatch).
//  bid <  18 : R[w,c,t] = sum_o dc_w[w,o] * conv1_w[w*128+o, c, t]
//  bid < 274 : gkT[w][j][c] = gk_w[c][w][j]
//  bid ==274 : fsum[o] = sum_oc fusion_w[o, 512+oc]
//  bid < 851 : A/P: A[w,o,m] = sum_oc fusion_w[o,w*128+oc]*cw[w,oc,m]; P col 512+
//  else      : x-side (1040 blocks): pad x->bf16 xpad + rowT/colF/colL partials.
//    ROUND-10: 8-channel threads (16 strips x 8 px, 16 cgroups x 8 ch):
//    2x f32x4 loads + ONE bf16x8 16-B store per pixel (was u16x4 8-B stores).
// ---------------------------------------------------------------------------
__global__ void kd1(const float* __restrict__ dc_w, const float* __restrict__ conv1_w,
                    const float* __restrict__ gk_w, const float* __restrict__ fusion_w,
                    const float* __restrict__ x,
                    float* __restrict__ R, float* __restrict__ gkT,
                    float* __restrict__ fsum, float* __restrict__ A,
                    float* __restrict__ P, u16* __restrict__ xpad,
                    float* __restrict__ rowT, float* __restrict__ colF,
                    float* __restrict__ colL) {
  const int bid = blockIdx.x, tid = threadIdx.x;
  __shared__ f32x4 ls[16][32];
  if (bid < 18) {
    int gid = bid * 256 + tid;                  // 0..4607
    int w = gid / 1152, m = gid % 1152;
    float s = 0.f;
    for (int o = 0; o < 128; ++o)
      s += dc_w[w * 128 + o] * conv1_w[(size_t)(w * 128 + o) * 1152 + m];
    R[gid] = s;
  } else if (bid < 274) {
    int gid = (bid - 18) * 256 + tid;           // 0..65535
    int w = gid >> 14, j = (gid >> 7) & 127, c = gid & 127;
    gkT[gid] = gk_w[c * 512 + w * 128 + j];
  } else if (bid == 274) {
    if (tid < 128) {
      float s = 0.f;
      for (int oc = 0; oc < 128; ++oc) s += fusion_w[tid * 640 + 512 + oc];
      fsum[tid] = s;
    }
  } else if (bid < 851) {
    int gid = (bid - 275) * 256 + tid;          // 0..147455
    int w = gid / 36864;
    int rem = gid % 36864;
    int o = rem / 288;
    int m = (rem % 288) * 4;
    const float* fw1 = fusion_w + o * 640 + w * 128;
    const float* fw4 = fusion_w + o * 640 + 512;
    const float* cw = conv1_w + (size_t)w * 128 * 1152 + m;
    float a0 = 0, a1 = 0, a2 = 0, a3 = 0, p0 = 0, p1 = 0, p2 = 0, p3 = 0;
    #pragma unroll 4
    for (int oc = 0; oc < 128; ++oc) {
      float f1 = fw1[oc], f4 = fw4[oc];
      float4 cv = *(const float4*)(cw + (size_t)oc * 1152);
      a0 += f1 * cv.x; a1 += f1 * cv.y; a2 += f1 * cv.z; a3 += f1 * cv.w;
      p0 += f4 * cv.x; p1 += f4 * cv.y; p2 += f4 * cv.z; p3 += f4 * cv.w;
    }
    float4* Ao = (float4*)(A + (size_t)(w * 128 + o) * 1152 + m);
    float4* Po = (float4*)(P + (size_t)(w * 128 + o) * 1152 + m);
    *Ao = make_float4(a0, a1, a2, a3);
    *Po = make_float4(p0, p1, p2, p3);
  } else {
    // ---- x-side: (rp, b) = padded row, batch ----
    const int kb = bid - 851;                   // 0..1039
    const int rp = kb % 130;
    const int b = kb / 130;
    const size_t xpb = ((size_t)b * 130 + rp) * 16640;
    const bf16x8 z = {0, 0, 0, 0, 0, 0, 0, 0};
    if (rp == 0 || rp == 129) {
      #pragma unroll
      for (int rr = 0; rr < 8; ++rr)
        *(bf16x8*)(xpad + xpb + (size_t)(rr * 256 + tid) * 8) = z;
      if (tid < 32)
        *(bf16x8*)(xpad + xpb + (size_t)(2048 + tid) * 8) = z;
      return;
    }
    const int r = rp - 1;
    // side pads (px 0 and px 129): 16 threads x 16B each
    if (tid < 16) {
      *(bf16x8*)(xpad + xpb + tid * 8) = z;
    } else if (tid < 32) {
      *(bf16x8*)(xpad + xpb + 129 * 128 + (tid - 16) * 8) = z;
    }
    const int s = tid >> 4;          // pixel strip 0..15 (8 px each)
    const int cg = tid & 15;         // channel group (8 ch)
    const int c0 = cg * 8;
    const float* xr = x + ((size_t)b * 16384 + (size_t)r * 128) * 128;
    f32x4 sumLo = {0.f, 0.f, 0.f, 0.f}, sumHi = {0.f, 0.f, 0.f, 0.f};
    f32x4 capLo = {0.f, 0.f, 0.f, 0.f}, capHi = {0.f, 0.f, 0.f, 0.f};
    #pragma unroll
    for (int qi = 0; qi < 8; ++qi) {
      const int q = s * 8 + qi;
      f32x4 vLo = *(const f32x4*)(xr + (size_t)q * 128 + c0);
      f32x4 vHi = *(const f32x4*)(xr + (size_t)q * 128 + c0 + 4);
      sumLo += vLo; sumHi += vHi;
      if (qi == 0 && (s == 0 || s == 8))  { capLo = vLo; capHi = vHi; }  // q == 0 / 64
      if (qi == 7 && (s == 7 || s == 15)) { capLo = vLo; capHi = vHi; }  // q == 63 / 127
      bf16x8 st = { (short)f2bf(vLo[0]), (short)f2bf(vLo[1]),
                    (short)f2bf(vLo[2]), (short)f2bf(vLo[3]),
                    (short)f2bf(vHi[0]), (short)f2bf(vHi[1]),
                    (short)f2bf(vHi[2]), (short)f2bf(vHi[3]) };
      *(bf16x8*)(xpad + xpb + (size_t)(q + 1) * 128 + c0) = st;
    }
    const size_t rT2 = ((size_t)b * 128 + r) * 2;
    if (s == 0) {
      *(f32x4*)(colF + (rT2 + 0) * 128 + c0) = capLo;
      *(f32x4*)(colF + (rT2 + 0) * 128 + c0 + 4) = capHi;
    } else if (s == 8) {
      *(f32x4*)(colF + (rT2 + 1) * 128 + c0) = capLo;
      *(f32x4*)(colF + (rT2 + 1) * 128 + c0 + 4) = capHi;
    } else if (s == 7) {
      *(f32x4*)(colL + (rT2 + 0) * 128 + c0) = capLo;
      *(f32x4*)(colL + (rT2 + 0) * 128 + c0 + 4) = capHi;
    } else if (s == 15) {
      *(f32x4*)(colL + (rT2 + 1) * 128 + c0) = capLo;
      *(f32x4*)(colL + (rT2 + 1) * 128 + c0 + 4) = capHi;
    }
    // rowT reduce: ls[s][cg*2+part] ; chunk g = cg*2+part covers c = g*4..g*4+3
    ls[s][cg * 2 + 0] = sumLo;
    ls[s][cg * 2 + 1] = sumHi;
    __syncthreads();
    if (tid < 64) {
      const int h = tid >> 5, g = tid & 31;
      f32x4 T = {0.f, 0.f, 0.f, 0.f};
      #pragma unroll
      for (int si = 0; si < 8; ++si) T += ls[h * 8 + si][g];
      *(f32x4*)(rowT + (rT2 + h) * 128 + g * 4) = T;
    }
  }
}

// ---------------------------------------------------------------------------
// K2: per-batch SE gate ww[b][w] from row partials (unchanged from round 7).
// ---------------------------------------------------------------------------
__global__ void k2_ww(const float* __restrict__ rowT, const float* __restrict__ colF,
                      const float* __restrict__ colL, const float* __restrict__ R,
                      const float* __restrict__ dc_b,
                      const float* __restrict__ l1_w, const float* __restrict__ l1_b,
                      const float* __restrict__ l2_w, const float* __restrict__ l2_b,
                      float* __restrict__ ww) {
  const int b = blockIdx.x;
  const int tid = threadIdx.x;
  const int w = tid >> 6, lane = tid & 63;
  __shared__ float red[4];
  const int i = w >> 1, j = w & 1;
  float partial = 0.f;
  #pragma unroll
  for (int k = 0; k < 2; ++k) {
    const int c = lane * 2 + k;
    const size_t rbase = ((size_t)b * 128 + i * 64) * 2 + j;
    float T = 0.f, cF = 0.f, cL = 0.f;
    #pragma unroll 4
    for (int ri = 0; ri < 64; ++ri) {
      const size_t idx = (rbase + (size_t)ri * 2) * 128 + c;
      T  += rowT[idx];
      cF += colF[idx];
      cL += colL[idx];
    }
    const size_t i0 = rbase * 128 + c;
    const size_t i63 = (rbase + 126) * 128 + c;
    const float rF = rowT[i0], rL = rowT[i63];
    const float c00 = colF[i0], c0L = colL[i0];
    const float cL0 = colF[i63], cLL = colL[i63];
    float S[9];
    S[0] = T - rL - cL + cLL;
    S[1] = T - rL;
    S[2] = T - rL - cF + cL0;
    S[3] = T - cL;
    S[4] = T;
    S[5] = T - cF;
    S[6] = T - rF - cL + c0L;
    S[7] = T - rF;
    S[8] = T - rF - cF + c00;
    const float* Rp = R + (w * 128 + c) * 9;
    #pragma unroll
    for (int t = 0; t < 9; ++t) partial += S[t] * Rp[t];
  }
  for (int off = 32; off > 0; off >>= 1) partial += __shfl_xor(partial, off, 64);
  if (lane == 0) red[w] = partial;
  __syncthreads();
  if (tid == 0) {
    float ww0[4];
    #pragma unroll
    for (int w2 = 0; w2 < 4; ++w2) ww0[w2] = red[w2] * (1.f / 4096.f) + dc_b[w2];
    float h1[16];
    for (int i2 = 0; i2 < 16; ++i2) {
      float s = l1_b[i2];
      #pragma unroll
      for (int w2 = 0; w2 < 4; ++w2) s += l1_w[i2 * 4 + w2] * ww0[w2];
      h1[i2] = 0.5f * s * (1.f + erff(s * 0.70710678118654752f));
    }
    for (int w2 = 0; w2 < 4; ++w2) {
      float s = l2_b[w2];
      for (int i2 = 0; i2 < 16; ++i2) s += l2_w[w2 * 16 + i2] * h1[i2];
      ww[b * 4 + w2] = 1.f / (1.f + expf(-s));
    }
  }
}

// ---------------------------------------------------------------------------
// K45: fused k4+k5 (unchanged from round 7).
// ---------------------------------------------------------------------------
__global__ void k45_keff(const float* __restrict__ A, const float* __restrict__ P,
                         const float* __restrict__ gkT, const float* __restrict__ ww,
                         const float* __restrict__ fsum, const float* __restrict__ gk_b,
                         u16* __restrict__ keff) {
  const int t = blockIdx.x >> 6;          // 0..8
  const int o0 = (blockIdx.x & 63) * 2;   // o-pair base
  const int tid = threadIdx.x;
  __shared__ float pl[2][4][128];
  __shared__ float al[2][4][128];
  __shared__ float red[2][2][4][128];
  #pragma unroll
  for (int rr = 0; rr < 4; ++rr) {
    const int idx = rr * 256 + tid;       // oi*512 + w*128 + j
    const int oi = idx >> 9, w = (idx >> 7) & 3, j = idx & 127;
    const size_t src = (size_t)(w * 128 + o0 + oi) * 1152 + j * 9 + t;
    pl[oi][w][j] = P[src];
    al[oi][w][j] = A[src];
  }
  __syncthreads();
  const int c = tid & 127, jh = tid >> 7;
  float acc[2][4];
  #pragma unroll
  for (int oi = 0; oi < 2; ++oi)
    #pragma unroll
    for (int w = 0; w < 4; ++w) acc[oi][w] = 0.f;
  const float* g = gkT + c;
  #pragma unroll 4
  for (int j = jh * 64; j < jh * 64 + 64; ++j) {
    const float g0 = g[0 * 16384 + j * 128];
    const float g1 = g[1 * 16384 + j * 128];
    const float g2 = g[2 * 16384 + j * 128];
    const float g3 = g[3 * 16384 + j * 128];
    #pragma unroll
    for (int oi = 0; oi < 2; ++oi) {
      acc[oi][0] += pl[oi][0][j] * g0;
      acc[oi][1] += pl[oi][1][j] * g1;
      acc[oi][2] += pl[oi][2][j] * g2;
      acc[oi][3] += pl[oi][3][j] * g3;
    }
  }
  #pragma unroll
  for (int oi = 0; oi < 2; ++oi)
    #pragma unroll
    for (int w = 0; w < 4; ++w) red[jh][oi][w][c] = acc[oi][w];
  __syncthreads();
  const int oi2 = tid >> 7, c2 = tid & 127;
  float m[4];
  #pragma unroll
  for (int w = 0; w < 4; ++w)
    m[w] = red[0][oi2][w][c2] + red[1][oi2][w][c2] + al[oi2][w][c2];
  const float base = fsum[o0 + oi2] * gk_b[c2];
  #pragma unroll
  for (int b = 0; b < 8; ++b) {
    float r = base;
    #pragma unroll
    for (int w = 0; w < 4; ++w) r += ww[b * 4 + w] * m[w];
    keff[(size_t)b * 147456 + (size_t)t * 16384 + (o0 + oi2) * 128 + c2] = f2bf(r);
  }
}

// ---------------------------------------------------------------------------
// K6: per-batch 3x3 C->C conv as 9 accumulated bf16 MFMA GEMMs (unchanged, R7).
// ---------------------------------------------------------------------------
__global__ __launch_bounds__(256, 2) void k6_conv(
    const u16* __restrict__ xpad, const u16* __restrict__ keff,
    const float* __restrict__ fusion_b, float* __restrict__ out) {
  __shared__ __align__(16) u16 alds[130 * 128];   // 33,280 B
  __shared__ __align__(16) u16 apad[256];         // DMA tail guard
  __shared__ __align__(16) u16 wlds[128 * 128];   // 32,768 B
  const int tid = threadIdx.x;
  const int blk = blockIdx.x;
  const int b = blk & 7;            // XCD affinity: batch <-> XCD
  const int p = blk >> 3;
  const int wid = tid >> 6;
  const int lane = tid & 63;
  const int wm = (wid & 1) * 64;
  const int wn = (wid >> 1) * 64;
  const int quad = lane >> 4;
  const int l16 = lane & 15;

  f32x4 acc[4][4];
  #pragma unroll
  for (int i = 0; i < 4; ++i)
    #pragma unroll
    for (int j = 0; j < 4; ++j)
      acc[i][j] = (f32x4){0.f, 0.f, 0.f, 0.f};

  const u16* kb = keff + (size_t)b * 147456;
  const u16* xb = xpad + (size_t)b * 130 * 16640;
  bf16x8 streg[8];
  (void)apad;

  auto stage_W_load = [&](int tap) {
    const u16* src = kb + tap * 16384;
    #pragma unroll
    for (int it = 0; it < 8; ++it) {
      const int chunk = it * 256 + tid;
      const int gs = chunk ^ ((chunk >> 4) & 7);
      streg[it] = *(const bf16x8*)(src + gs * 8);
    }
  };
  auto stage_W_write = [&]() {
    #pragma unroll
    for (int it = 0; it < 8; ++it)
      *(bf16x8*)(wlds + (it * 256 + tid) * 8) = streg[it];
  };
  auto stage_A_dma = [&](int prow) {
    const u16* src = xb + (size_t)prow * 16640;
    #pragma unroll
    for (int r = 0; r < 8; ++r) {
      const int chunk = (wid * 8 + r) * 64 + lane;
      const int gs = chunk ^ ((chunk >> 4) & 7);
      __builtin_amdgcn_global_load_lds(
          (const __attribute__((address_space(1))) unsigned int*)(src + (size_t)gs * 8),
          (__attribute__((address_space(3))) unsigned int*)(alds + (wid * 8 + r) * 512),
          16, 0, 0);
    }
    if (tid < 32) {
      const int chunk = 2048 + tid;
      const int gs = chunk ^ ((chunk >> 4) & 7);
      __builtin_amdgcn_global_load_lds(
          (const __attribute__((address_space(1))) unsigned int*)(src + (size_t)gs * 8),
          (__attribute__((address_space(3))) unsigned int*)(alds + 2048 * 8),
          16, 0, 0);
    }
  };

  stage_W_load(0);
  stage_A_dma(p);
  stage_W_write();
  __syncthreads();   // drains vmcnt -> DMA complete, W visible

  for (int tap = 0; tap < 9; ++tap) {
    if (tap < 8) stage_W_load(tap + 1);         // global->reg, overlaps MFMA
    const int dw = tap % 3 - 1;
    const int pixoff = 1 + dw;
    #pragma unroll
    for (int kc = 0; kc < 4; ++kc) {
      const int c0 = kc * 32 + quad * 8;
      bf16x8 a[4], bb[4];
      #pragma unroll
      for (int i = 0; i < 4; ++i) {
        const int pix = pixoff + wm + i * 16 + l16;
        const int off = (pix * 128 + c0) ^ ((pix & 7) << 3);
        a[i] = *(const bf16x8*)(alds + off);
      }
      #pragma unroll
      for (int j = 0; j < 4; ++j) {
        const int row = wn + j * 16 + l16;
        const int off = (row * 128 + c0) ^ ((row & 7) << 3);
        bb[j] = *(const bf16x8*)(wlds + off);
      }
      #pragma unroll
      for (int i = 0; i < 4; ++i)
        #pragma unroll
        for (int j = 0; j < 4; ++j)
          acc[i][j] = __builtin_amdgcn_mfma_f32_16x16x32_bf16(a[i], bb[j], acc[i][j], 0, 0, 0);
    }
    __syncthreads();                            // all waves done reading alds/wlds
    if (tap < 8) {
      stage_W_write();                          // vmcnt waits streg, then ds_write
      if (tap % 3 == 2) stage_A_dma(p + (tap + 1) / 3);  // next dh row
      __syncthreads();                          // drains vmcnt -> DMA + writes visible
    }
  }

  float fb[4];
  #pragma unroll
  for (int j = 0; j < 4; ++j) fb[j] = fusion_b[wn + j * 16 + l16];
  float* outb = out + ((size_t)b * 16384 + (size_t)p * 128) * 128;
  #pragma unroll
  for (int i = 0; i < 4; ++i)
    #pragma unroll
    for (int r = 0; r < 4; ++r) {
      const int m = wm + i * 16 + quad * 4 + r;
      #pragma unroll
      for (int j = 0; j < 4; ++j)
        outb[(size_t)m * 128 + (wn + j * 16 + l16)] = acc[i][j][r] + fb[j];
    }
}

extern "C" void kernel_launch(void* const* d_in, const int* in_sizes, int n_in,
                              void* d_out, int out_size, void* d_ws, size_t ws_size,
                              hipStream_t stream) {
  const float* x        = (const float*)d_in[0];
  const float* conv1_w  = (const float*)d_in[1];
  const float* dc_w     = (const float*)d_in[2];
  const float* dc_b     = (const float*)d_in[3];
  const float* l1_w     = (const float*)d_in[4];
  const float* l1_b     = (const float*)d_in[5];
  const float* l2_w     = (const float*)d_in[6];
  const float* l2_b     = (const float*)d_in[7];
  const float* gk_w     = (const float*)d_in[8];
  const float* gk_b     = (const float*)d_in[9];
  const float* fusion_w = (const float*)d_in[10];
  const float* fusion_b = (const float*)d_in[11];
  float* out = (float*)d_out;
  char* ws = (char*)d_ws;

  float* wwp  = (float*)(ws + OFF_WW);
  float* R    = (float*)(ws + OFF_R);
  float* fsum = (float*)(ws + OFF_FSUM);
  float* gkT  = (float*)(ws + OFF_GKT);
  float* A    = (float*)(ws + OFF_A);
  float* P    = (float*)(ws + OFF_P);
  float* rowT = (float*)(ws + OFF_M);
  float* colF = (float*)(ws + OFF_M + 1048576u);
  float* colL = (float*)(ws + OFF_KEFF);        // overlays keff; consumed by k2 before k45 writes
  u16* keff   = (u16*)(ws + OFF_KEFF);
  u16* xpad   = (u16*)(ws + OFF_XPAD);

  // 4 dispatches: {weights + x-side} prep, tiny ww, keff, conv.
  kd1<<<1891, 256, 0, stream>>>(dc_w, conv1_w, gk_w, fusion_w, x,
                                R, gkT, fsum, A, P, xpad, rowT, colF, colL);
  k2_ww<<<8, 256, 0, stream>>>(rowT, colF, colL, R, dc_b, l1_w, l1_b, l2_w, l2_b, wwp);
  k45_keff<<<576, 256, 0, stream>>>(A, P, gkT, wwp, fsum, gk_b, keff);
  k6_conv<<<1024, 256, 0, stream>>>(xpad, keff, fusion_b, out);
}